// Round 10
// baseline (605.180 us; speedup 1.0000x reference)
//
#include <hip/hip_runtime.h>
#include <math.h>

#define NSTEPS 3000
#define NWALK  1048576
#define BLOCK  1024              // R10: 16 waves/block -> 6.25% compaction grain
#define NBD    (NWALK / BLOCK)   // 1024 dense blocks
#define NDENSE 6                 // dense rounds cover t in [0, 384), 64 steps each
#define CHUNK  64
#define NWAVES (BLOCK / 64)
#define NBT    4096              // tail grid: 16384 waves
#define NKEYS  3072

// FMA contraction (R8: passed, absmax identical 0.09375 — zero flips).
#define MAD(a, b, c) __fmaf_rn((a), (b), (c))

// Ping-pong survivor lists (i, p-bits), per-round counts, precomputed keys.
__device__ uint2    g_list[2][NWALK];
__device__ uint32_t g_cnt[16];
__device__ uint2    g_keys[NKEYS];

// Threefry-2x32, 20 rounds, exactly JAX's schedule.
__device__ __forceinline__ void tf2x32(uint32_t k0, uint32_t k1,
                                       uint32_t x0, uint32_t x1,
                                       uint32_t& o0, uint32_t& o1) {
  uint32_t ks2 = k0 ^ k1 ^ 0x1BD11BDAu;
  x0 += k0; x1 += k1;
#define TFR(r) { x0 += x1; x1 = (x1 << r) | (x1 >> (32 - r)); x1 ^= x0; }
  TFR(13) TFR(15) TFR(26) TFR(6)
  x0 += k1;  x1 += ks2 + 1u;
  TFR(17) TFR(29) TFR(16) TFR(24)
  x0 += ks2; x1 += k0 + 2u;
  TFR(13) TFR(15) TFR(26) TFR(6)
  x0 += k0;  x1 += k1 + 3u;
  TFR(17) TFR(29) TFR(16) TFR(24)
  x0 += k1;  x1 += ks2 + 4u;
  TFR(13) TFR(15) TFR(26) TFR(6)
  x0 += ks2; x1 += k0 + 5u;
#undef TFR
  o0 = x0; o1 = x1;
}

// init: per-step folded split keys (counter (0,t), key (0,0)) + zero counts.
__global__ void init_kernel() {   // <<<NKEYS/256, 256>>>
  int t = blockIdx.x * 256 + threadIdx.x;
  uint32_t a, b;
  tf2x32(0u, 0u, 0u, (uint32_t)t, a, b);
  g_keys[t] = make_uint2(a, b);
  if (blockIdx.x == 0 && threadIdx.x < 16) g_cnt[threadIdx.x] = 0u;
}

// XLA CPU's log.f32 (Cephes/Eigen-3.3 plog), FMA-contracted (R8-verified).
__device__ __forceinline__ float xla_cpu_log_f32(float s) {
  uint32_t bits = __float_as_uint(s);
  int emm0 = (int)(bits >> 23) - 0x7f;
  float e = __fadd_rn((float)emm0, 1.0f);
  float m = __uint_as_float((bits & 0x007fffffu) | 0x3f000000u);
  bool mlt = m < 0.70710677f;
  float tmp = mlt ? m : 0.0f;
  float x = __fsub_rn(m, 1.0f);
  e = __fsub_rn(e, mlt ? 1.0f : 0.0f);
  x = __fadd_rn(x, tmp);
  float x2 = __fmul_rn(x, x);
  float x3 = __fmul_rn(x2, x);
  float y, y1, y2;
  y  = MAD(7.0376836292e-2f,  x, -1.1514610310e-1f);
  y1 = MAD(-1.2420140846e-1f, x,  1.4249322787e-1f);
  y2 = MAD(2.0000714765e-1f,  x, -2.4999993993e-1f);
  y  = MAD(y,  x,  1.1676998740e-1f);
  y1 = MAD(y1, x, -1.6668057665e-1f);
  y2 = MAD(y2, x,  3.3333331174e-1f);
  y  = MAD(y, x3, y1);
  y  = MAD(y, x3, y2);
  y  = __fmul_rn(y, x3);
  y  = MAD(e, -2.12194440e-4f, y);
  x  = MAD(x2, -0.5f, x);
  x  = __fadd_rn(x, y);
  x  = MAD(e, 0.693359375f, x);
  return x;
}

// XLA EmitErfInv f32 (Giles): w = -log((1-x)*(1+x)), branch at w<5.
__device__ __forceinline__ float xla_erfinv_f32(float x) {
  float s = __fmul_rn(__fsub_rn(1.0f, x), __fadd_rn(1.0f, x));
  float w = -xla_cpu_log_f32(s);
  float p;
  if (w < 5.0f) {
    float v = __fsub_rn(w, 2.5f);
    p = 2.81022636e-08f;
    p = MAD(p, v, 3.43273939e-07f);
    p = MAD(p, v, -3.5233877e-06f);
    p = MAD(p, v, -4.39150654e-06f);
    p = MAD(p, v, 0.00021858087f);
    p = MAD(p, v, -0.00125372503f);
    p = MAD(p, v, -0.00417768164f);
    p = MAD(p, v, 0.246640727f);
    p = MAD(p, v, 1.50140941f);
  } else {
    float v = __fsub_rn(__fsqrt_rn(w), 3.0f);
    p = -0.000200214257f;
    p = MAD(p, v, 0.000100950558f);
    p = MAD(p, v, 0.00134934322f);
    p = MAD(p, v, -0.00367342844f);
    p = MAD(p, v, 0.00573950773f);
    p = MAD(p, v, -0.0076224613f);
    p = MAD(p, v, 0.00943887047f);
    p = MAD(p, v, 1.00167406f);
    p = MAD(p, v, 2.83297682f);
  }
  return __fmul_rn(p, x);
}

__device__ __forceinline__ float normal_from_bits(uint32_t bits) {
  const float MINVAL = __uint_as_float(0xBF7FFFFFu);   // nextafter(-1,0)
  float f = __uint_as_float((bits >> 9) | 0x3F800000u) - 1.0f;
  float u = MAD(f, 2.0f, MINVAL);
  u = fmaxf(MINVAL, u);
  const float SQRT2 = __uint_as_float(0x3FB504F3u);
  return __fmul_rn(SQRT2, xla_erfinv_f32(u));
}

// Dense round. R10: IN-KERNEL RECOMPACTION every 16 steps. A dead lane costs
// issue until its whole WAVE is dead (exec-mask skips lanes, not waves); with
// 16 waves/block and an LDS exchange at each 16-step boundary, survivors pack
// into the leading waves and trailing waves become execz-skipped. The proven
// 16-step inner body (R9) is byte-identical; compaction code is block-uniform
// control between unrolled chunks. Deferred death-stores flush before each
// exchange so lane contexts can migrate. Walker op sequences are (t,i)-keyed,
// lane-placement-invariant -> outputs unchanged.
template<int R>
__device__ __forceinline__
void ddm_round_body(const float* __restrict__ sv_p, const float* __restrict__ rate_p,
                    const float* __restrict__ ndt_p, const float* __restrict__ thr_p,
                    const float* __restrict__ noise_p, const float* __restrict__ dt_p,
                    const int* __restrict__ nw_p, float* __restrict__ out) {
  constexpr int t0 = R * CHUNK;
  int nw = *nw_p;
  uint32_t count = (R == 0) ? (uint32_t)nw : g_cnt[R];
  if (blockIdx.x * BLOCK >= count) return;     // block-uniform: no barriers yet

  __shared__ uint2    skeys[CHUNK];
  __shared__ uint2    s_exch[BLOCK];
  __shared__ uint32_t s_woff[NWAVES];
  __shared__ uint32_t s_base;
  if (threadIdx.x < CHUNK) {
    uint32_t a, b;
    tf2x32(0u, 0u, 0u, (uint32_t)(t0 + threadIdx.x), a, b);
    skeys[threadIdx.x] = make_uint2(a, b);
  }
  __syncthreads();

  uint32_t slot = blockIdx.x * BLOCK + threadIdx.x;
  bool alive = slot < count;                   // no wave early-return: barriers below
  float sv = *sv_p, rate = *rate_p, ndt = *ndt_p, thr = *thr_p,
        noise = *noise_p, dt = *dt_p;
  float rate_dt = __fmul_rn(rate, dt);
  float sqrt_dt = __fsqrt_rn(dt);
  int lane = threadIdx.x & 63;
  int wv = threadIdx.x >> 6;

  int i = 0; float p = 0.0f;
  if (alive) {
    if (R == 0) { i = (int)slot; p = __fadd_rn(0.0f, sv); }
    else { uint2 e = g_list[R & 1][slot]; i = (int)e.x; p = __uint_as_float(e.y); }
  }

  int death_s = -1;
  #pragma clang loop unroll(disable)
  for (int c = 0; c < CHUNK / 16; ++c) {       // runtime outer: code stays 16-step
    if (c > 0) {
      // ---- flush pending deaths (context is about to migrate) ----
      if (death_s >= 0) {
        float rts = (float)(t0 + death_s + 1);
        out[i] = __fadd_rn(ndt, __fmul_rn(rts, dt));
        out[nw + i] = (p <= -thr) ? 0.0f : 1.0f;
        death_s = -1;
      }
      // ---- block recompaction: survivors -> leading waves ----
      uint64_t m = __ballot(alive);
      if (lane == 0) s_woff[wv] = (uint32_t)__popcll((unsigned long long)m);
      __syncthreads();
      uint32_t total = 0, base = 0;
      #pragma unroll
      for (int w = 0; w < NWAVES; ++w) {
        uint32_t cw = s_woff[w];
        if (w < wv) base += cw;
        total += cw;
      }
      if (total == 0) break;                   // block-uniform (same LDS inputs)
      if (alive) {
        uint32_t pos = base +
            (uint32_t)__popcll((unsigned long long)(m & ((1ull << lane) - 1ull)));
        s_exch[pos] = make_uint2((uint32_t)i, __float_as_uint(p));
      }
      __syncthreads();
      alive = threadIdx.x < total;
      if (alive) {
        uint2 e = s_exch[threadIdx.x];
        i = (int)e.x; p = __uint_as_float(e.y);
      }
    }
    #pragma unroll
    for (int j = 0; j < 16; ++j) {
      int s = c * 16 + j;
      if (alive) {                             // fully-dead waves: execz skip
        uint2 k = skeys[s];                    // uniform s: broadcast, no conflicts
        uint32_t b1, b2;
        tf2x32(k.x, k.y, 0u, (uint32_t)i, b1, b2);
        float z = normal_from_bits(b1 ^ b2);
        p = __fadd_rn(p, __fmul_rn(__fadd_rn(rate_dt, __fmul_rn(noise, z)), sqrt_dt));
        if (!(fabsf(p) < thr)) { death_s = s; alive = false; }
      }
    }
  }
  if (death_s >= 0) {                          // flush last-chunk deaths
    float rts = (float)(t0 + death_s + 1);
    out[i] = __fadd_rn(ndt, __fmul_rn(rts, dt));
    out[nw + i] = (p <= -thr) ? 0.0f : 1.0f;
  }

  // ---- per-block aggregated epilogue: ONE atomic per block ----
  uint64_t m = __ballot(alive);
  if (lane == 0) s_woff[wv] = (uint32_t)__popcll((unsigned long long)m);
  __syncthreads();
  if (threadIdx.x == 0) {
    uint32_t tot = 0;
    #pragma unroll
    for (int w = 0; w < NWAVES; ++w) {
      uint32_t c = s_woff[w]; s_woff[w] = tot; tot += c;   // exclusive prefix
    }
    s_base = tot ? atomicAdd(&g_cnt[R + 1], tot) : 0u;
  }
  __syncthreads();
  if (alive) {
    uint32_t pos = s_base + s_woff[wv] +
                   (uint32_t)__popcll((unsigned long long)(m & ((1ull << lane) - 1ull)));
    g_list[(R + 1) & 1][pos] = make_uint2((uint32_t)i, __float_as_uint(p));
  }
}

// Distinct kernel names per round so rocprof top-k decomposes the timeline.
#define ARGS (const float* __restrict__ sv, const float* __restrict__ rate,   \
              const float* __restrict__ ndt, const float* __restrict__ thr,   \
              const float* __restrict__ noise, const float* __restrict__ dt,  \
              const int* __restrict__ nw, float* __restrict__ out)
#define DEFROUND(NAME, R)                                                     \
  __global__ __launch_bounds__(BLOCK) void NAME ARGS {                        \
    ddm_round_body<R>(sv, rate, ndt, thr, noise, dt, nw, out);                \
  }
DEFROUND(ddm_r0, 0)   DEFROUND(ddm_r1, 1)   DEFROUND(ddm_r2, 2)
DEFROUND(ddm_r3, 3)   DEFROUND(ddm_r4, 4)   DEFROUND(ddm_r5, 5)
#undef DEFROUND
#undef ARGS

// readlane broadcast of a float (forces v_readlane, not ds_bpermute).
__device__ __forceinline__ float rdlane_f(float v, int j) {
  return __uint_as_float((uint32_t)__builtin_amdgcn_readlane((int)__float_as_uint(v), j));
}

// Tail: ONE WALKER PER WAVE (unchanged from R7/R9 — proven).
__global__ __launch_bounds__(256)
void ddm_tail(const float* __restrict__ sv_p, const float* __restrict__ rate_p,
              const float* __restrict__ ndt_p, const float* __restrict__ thr_p,
              const float* __restrict__ noise_p, const float* __restrict__ dt_p,
              const int* __restrict__ nw_p, float* __restrict__ out,
              int round, int t0) {
  int nw = *nw_p;
  float rate = *rate_p, ndt = *ndt_p, thr = *thr_p,
        noise = *noise_p, dt = *dt_p;
  float rate_dt = __fmul_rn(rate, dt);
  float sqrt_dt = __fsqrt_rn(dt);

  int lane = threadIdx.x & 63;
  uint32_t wave = blockIdx.x * (256 / 64) + (threadIdx.x >> 6);
  uint32_t nwaves = gridDim.x * (256 / 64);
  uint32_t count = g_cnt[round];

  for (uint32_t k = wave; k < count; k += nwaves) {
    uint2 e = g_list[round & 1][k];
    int i = (int)e.x;
    float p = __uint_as_float(e.y);        // wave-uniform from here on
    int t = t0;
    int rts_i = NSTEPS;
    bool done = false;
    while (!done) {
      int valid = NSTEPS - t; if (valid > 64) valid = 64;
      int tl = t + (lane < valid ? lane : valid - 1);
      uint2 kk = g_keys[tl];               // coalesced 8B, L2-resident
      uint32_t b1, b2;
      tf2x32(kk.x, kk.y, 0u, (uint32_t)i, b1, b2);
      float z = normal_from_bits(b1 ^ b2);
      float q = __fmul_rn(__fadd_rn(rate_dt, __fmul_rn(noise, z)), sqrt_dt);

      if (valid == 64) {
        // ---- branchless exact fold, quarter-snapshotted ----
        float s0 = p, mx0 = 0.0f, mx1 = 0.0f, mx2 = 0.0f, mx3 = 0.0f;
        #pragma unroll
        for (int j = 0; j < 16; ++j) {
          p = __fadd_rn(p, rdlane_f(q, j));  mx0 = fmaxf(mx0, fabsf(p));
        }
        float s1 = p;
        #pragma unroll
        for (int j = 16; j < 32; ++j) {
          p = __fadd_rn(p, rdlane_f(q, j));  mx1 = fmaxf(mx1, fabsf(p));
        }
        float s2 = p;
        #pragma unroll
        for (int j = 32; j < 48; ++j) {
          p = __fadd_rn(p, rdlane_f(q, j));  mx2 = fmaxf(mx2, fabsf(p));
        }
        float s3 = p;
        #pragma unroll
        for (int j = 48; j < 64; ++j) {
          p = __fadd_rn(p, rdlane_f(q, j));  mx3 = fmaxf(mx3, fabsf(p));
        }
        if (fmaxf(fmaxf(mx0, mx1), fmaxf(mx2, mx3)) >= thr) {
          // death block: first crossing lives in the FIRST quarter w/ mx>=thr
          float pr; int jb;
          if      (mx0 >= thr) { pr = s0; jb = 0;  }
          else if (mx1 >= thr) { pr = s1; jb = 16; }
          else if (mx2 >= thr) { pr = s2; jb = 32; }
          else                 { pr = s3; jb = 48; }
          for (int j = 0; j < 16; ++j) {   // exact re-scan from snapshot
            pr = __fadd_rn(pr, rdlane_f(q, jb + j));
            if (!(fabsf(pr) < thr)) {
              rts_i = t + jb + j + 1; p = pr; done = true; break;
            }
          }
        } else {
          t += 64;
          if (t >= NSTEPS) done = true;    // ran out the clock: rts = 3000
        }
      } else {
        // rare partial final block: original checked scan
        for (int j = 0; j < valid; ++j) {
          float qj = rdlane_f(q, j);
          p = __fadd_rn(p, qj);
          if (!(fabsf(p) < thr)) { rts_i = t + j + 1; done = true; break; }
        }
        if (!done) {
          t += valid;
          if (t >= NSTEPS) done = true;
        }
      }
    }
    if (lane == 0) {
      out[i] = __fadd_rn(ndt, __fmul_rn((float)rts_i, dt));
      out[nw + i] = (p <= -thr) ? 0.0f : 1.0f;
    }
  }
}

extern "C" void kernel_launch(void* const* d_in, const int* in_sizes, int n_in,
                              void* d_out, int out_size, void* d_ws, size_t ws_size,
                              hipStream_t stream) {
  const float* sv    = (const float*)d_in[0];
  const float* rate  = (const float*)d_in[1];
  const float* ndt   = (const float*)d_in[2];
  const float* thr   = (const float*)d_in[3];
  const float* noise = (const float*)d_in[4];
  const float* dt    = (const float*)d_in[5];
  const int*   nw    = (const int*)d_in[6];
  float* out = (float*)d_out;

  init_kernel<<<NKEYS / 256, 256, 0, stream>>>();
  ddm_r0<<<NBD, BLOCK, 0, stream>>>(sv, rate, ndt, thr, noise, dt, nw, out);
  ddm_r1<<<NBD, BLOCK, 0, stream>>>(sv, rate, ndt, thr, noise, dt, nw, out);
  ddm_r2<<<NBD, BLOCK, 0, stream>>>(sv, rate, ndt, thr, noise, dt, nw, out);
  ddm_r3<<<NBD, BLOCK, 0, stream>>>(sv, rate, ndt, thr, noise, dt, nw, out);
  ddm_r4<<<NBD, BLOCK, 0, stream>>>(sv, rate, ndt, thr, noise, dt, nw, out);
  ddm_r5<<<NBD, BLOCK, 0, stream>>>(sv, rate, ndt, thr, noise, dt, nw, out);
  ddm_tail<<<NBT, 256, 0, stream>>>(sv, rate, ndt, thr, noise, dt, nw, out,
                                    NDENSE, NDENSE * CHUNK);
}

// Round 11
// 518.645 us; speedup vs baseline: 1.1668x; 1.1668x over previous
//
#include <hip/hip_runtime.h>
#include <math.h>

#define NSTEPS 3000
#define NWALK  1048576
#define BLOCK  256               // R11: revert to R9 config (best: 521.7us)
#define NBD    (NWALK / BLOCK)   // 4096 dense blocks
#define NDENSE 6                 // dense rounds cover t in [0, 384), 64 steps each
#define CHUNK  64
#define NBT    4096              // tail grid: 16384 waves
#define NKEYS  3072

// FMA contraction (R8: passed, absmax identical 0.09375 — zero flips).
#define MAD(a, b, c) __fmaf_rn((a), (b), (c))

// Ping-pong survivor lists (i, p-bits), per-round counts, precomputed keys.
__device__ uint2    g_list[2][NWALK];
__device__ uint32_t g_cnt[16];
__device__ uint2    g_keys[NKEYS];

// Threefry-2x32, 20 rounds, exactly JAX's schedule.
__device__ __forceinline__ void tf2x32(uint32_t k0, uint32_t k1,
                                       uint32_t x0, uint32_t x1,
                                       uint32_t& o0, uint32_t& o1) {
  uint32_t ks2 = k0 ^ k1 ^ 0x1BD11BDAu;
  x0 += k0; x1 += k1;
#define TFR(r) { x0 += x1; x1 = (x1 << r) | (x1 >> (32 - r)); x1 ^= x0; }
  TFR(13) TFR(15) TFR(26) TFR(6)
  x0 += k1;  x1 += ks2 + 1u;
  TFR(17) TFR(29) TFR(16) TFR(24)
  x0 += ks2; x1 += k0 + 2u;
  TFR(13) TFR(15) TFR(26) TFR(6)
  x0 += k0;  x1 += k1 + 3u;
  TFR(17) TFR(29) TFR(16) TFR(24)
  x0 += k1;  x1 += ks2 + 4u;
  TFR(13) TFR(15) TFR(26) TFR(6)
  x0 += ks2; x1 += k0 + 5u;
#undef TFR
  o0 = x0; o1 = x1;
}

// init: per-step folded split keys (counter (0,t), key (0,0)) + zero counts.
__global__ void init_kernel() {   // <<<NKEYS/256, 256>>>
  int t = blockIdx.x * 256 + threadIdx.x;
  uint32_t a, b;
  tf2x32(0u, 0u, 0u, (uint32_t)t, a, b);
  g_keys[t] = make_uint2(a, b);
  if (blockIdx.x == 0 && threadIdx.x < 16) g_cnt[threadIdx.x] = 0u;
}

// XLA CPU's log.f32 (Cephes/Eigen-3.3 plog), FMA-contracted (R8-verified).
__device__ __forceinline__ float xla_cpu_log_f32(float s) {
  uint32_t bits = __float_as_uint(s);
  int emm0 = (int)(bits >> 23) - 0x7f;
  float e = __fadd_rn((float)emm0, 1.0f);
  float m = __uint_as_float((bits & 0x007fffffu) | 0x3f000000u);
  bool mlt = m < 0.70710677f;
  float tmp = mlt ? m : 0.0f;
  float x = __fsub_rn(m, 1.0f);
  e = __fsub_rn(e, mlt ? 1.0f : 0.0f);
  x = __fadd_rn(x, tmp);
  float x2 = __fmul_rn(x, x);
  float x3 = __fmul_rn(x2, x);
  float y, y1, y2;
  y  = MAD(7.0376836292e-2f,  x, -1.1514610310e-1f);
  y1 = MAD(-1.2420140846e-1f, x,  1.4249322787e-1f);
  y2 = MAD(2.0000714765e-1f,  x, -2.4999993993e-1f);
  y  = MAD(y,  x,  1.1676998740e-1f);
  y1 = MAD(y1, x, -1.6668057665e-1f);
  y2 = MAD(y2, x,  3.3333331174e-1f);
  y  = MAD(y, x3, y1);
  y  = MAD(y, x3, y2);
  y  = __fmul_rn(y, x3);
  y  = MAD(e, -2.12194440e-4f, y);
  x  = MAD(x2, -0.5f, x);
  x  = __fadd_rn(x, y);
  x  = MAD(e, 0.693359375f, x);
  return x;
}

// XLA EmitErfInv f32 (Giles): w = -log((1-x)*(1+x)), branch at w<5.
__device__ __forceinline__ float xla_erfinv_f32(float x) {
  float s = __fmul_rn(__fsub_rn(1.0f, x), __fadd_rn(1.0f, x));
  float w = -xla_cpu_log_f32(s);
  float p;
  if (w < 5.0f) {
    float v = __fsub_rn(w, 2.5f);
    p = 2.81022636e-08f;
    p = MAD(p, v, 3.43273939e-07f);
    p = MAD(p, v, -3.5233877e-06f);
    p = MAD(p, v, -4.39150654e-06f);
    p = MAD(p, v, 0.00021858087f);
    p = MAD(p, v, -0.00125372503f);
    p = MAD(p, v, -0.00417768164f);
    p = MAD(p, v, 0.246640727f);
    p = MAD(p, v, 1.50140941f);
  } else {
    float v = __fsub_rn(__fsqrt_rn(w), 3.0f);
    p = -0.000200214257f;
    p = MAD(p, v, 0.000100950558f);
    p = MAD(p, v, 0.00134934322f);
    p = MAD(p, v, -0.00367342844f);
    p = MAD(p, v, 0.00573950773f);
    p = MAD(p, v, -0.0076224613f);
    p = MAD(p, v, 0.00943887047f);
    p = MAD(p, v, 1.00167406f);
    p = MAD(p, v, 2.83297682f);
  }
  return __fmul_rn(p, x);
}

// R11: raw erfinv value from rng bits — the sqrt(2) and (rate,noise,sqrt_dt)
// scalars are folded into uniform A/B2 (one fma per step). The fmax(MINVAL,u)
// clamp is provably a no-op (u = fma(f,2,MINVAL), f>=0 -> u>=MINVAL exactly;
// MINVAL representable, rounding cannot go below): removed bit-exactly.
__device__ __forceinline__ float einv_from_bits(uint32_t bits) {
  const float MINVAL = __uint_as_float(0xBF7FFFFFu);   // nextafter(-1,0)
  float f = __uint_as_float((bits >> 9) | 0x3F800000u) - 1.0f;
  float u = MAD(f, 2.0f, MINVAL);
  return xla_erfinv_f32(u);
}

#define SQRT2_F __uint_as_float(0x3FB504F3u)

// Dense round: R9-proven shape (LDS-key broadcast, predicated 4x16 partially
// unrolled body, NO per-step ballots/breaks/barriers), per-BLOCK aggregated
// atomic, deferred death-store. R10 lesson (twice-proven with R1): in-loop
// survivor compaction never pays — barrier variance + deep-round CU
// starvation exceed dead-lane recovery. Structure frozen; R11 shaves instr:
// per step p += fma(B2, erfinv_raw, A) with A = rate_dt*sqrt_dt,
// B2 = noise*sqrt_dt*sqrt2 (uniform scalars, 1-ulp-class refactor, same
// perturbation class as R8's verified FMA contraction).
template<int R>
__device__ __forceinline__
void ddm_round_body(const float* __restrict__ sv_p, const float* __restrict__ rate_p,
                    const float* __restrict__ ndt_p, const float* __restrict__ thr_p,
                    const float* __restrict__ noise_p, const float* __restrict__ dt_p,
                    const int* __restrict__ nw_p, float* __restrict__ out) {
  constexpr int t0 = R * CHUNK;
  int nw = *nw_p;
  uint32_t count = (R == 0) ? (uint32_t)nw : g_cnt[R];
  if (blockIdx.x * BLOCK >= count) return;     // block-uniform: no barriers yet

  __shared__ uint2    skeys[CHUNK];
  __shared__ uint32_t s_woff[BLOCK / 64];
  __shared__ uint32_t s_base;
  if (threadIdx.x < CHUNK) {
    uint32_t a, b;
    tf2x32(0u, 0u, 0u, (uint32_t)(t0 + threadIdx.x), a, b);
    skeys[threadIdx.x] = make_uint2(a, b);
  }
  __syncthreads();

  uint32_t slot = blockIdx.x * BLOCK + threadIdx.x;
  bool alive = slot < count;                   // no wave early-return: barriers below
  float sv = *sv_p, rate = *rate_p, ndt = *ndt_p, thr = *thr_p,
        noise = *noise_p, dt = *dt_p;
  float rate_dt = __fmul_rn(rate, dt);
  float sqrt_dt = __fsqrt_rn(dt);
  float A  = __fmul_rn(rate_dt, sqrt_dt);                    // uniform
  float B2 = __fmul_rn(__fmul_rn(noise, sqrt_dt), SQRT2_F);  // uniform
  int lane = threadIdx.x & 63;
  int wv = threadIdx.x >> 6;

  int i = 0; float p = 0.0f;
  if (alive) {
    if (R == 0) { i = (int)slot; p = __fadd_rn(0.0f, sv); }
    else { uint2 e = g_list[R & 1][slot]; i = (int)e.x; p = __uint_as_float(e.y); }
  }

  int death_s = -1;
  #pragma clang loop unroll(disable)
  for (int c = 0; c < CHUNK / 16; ++c) {       // runtime outer: code stays 16-step
    #pragma unroll
    for (int j = 0; j < 16; ++j) {
      int s = c * 16 + j;
      if (alive) {                             // dead waves: execz skip, ~free
        uint2 k = skeys[s];                    // uniform s: broadcast, no conflicts
        uint32_t b1, b2;
        tf2x32(k.x, k.y, 0u, (uint32_t)i, b1, b2);
        float e = einv_from_bits(b1 ^ b2);
        p = __fadd_rn(p, MAD(B2, e, A));
        if (!(fabsf(p) < thr)) { death_s = s; alive = false; }
      }
    }
  }
  if (death_s >= 0) {                          // once per dying lane, post-loop
    float rts = (float)(t0 + death_s + 1);     // exact int == accumulated +1.0f
    out[i] = __fadd_rn(ndt, __fmul_rn(rts, dt));
    out[nw + i] = (p <= -thr) ? 0.0f : 1.0f;
  }

  // ---- per-block aggregated compaction: ONE atomic per block ----
  uint64_t m = __ballot(alive);
  if (lane == 0) s_woff[wv] = (uint32_t)__popcll((unsigned long long)m);
  __syncthreads();
  if (threadIdx.x == 0) {
    uint32_t tot = 0;
    #pragma unroll
    for (int w = 0; w < BLOCK / 64; ++w) {
      uint32_t c = s_woff[w]; s_woff[w] = tot; tot += c;   // exclusive prefix
    }
    s_base = tot ? atomicAdd(&g_cnt[R + 1], tot) : 0u;
  }
  __syncthreads();
  if (alive) {
    uint32_t pos = s_base + s_woff[wv] +
                   (uint32_t)__popcll((unsigned long long)(m & ((1ull << lane) - 1ull)));
    g_list[(R + 1) & 1][pos] = make_uint2((uint32_t)i, __float_as_uint(p));
  }
}

// Distinct kernel names per round so rocprof top-k decomposes the timeline.
#define ARGS (const float* __restrict__ sv, const float* __restrict__ rate,   \
              const float* __restrict__ ndt, const float* __restrict__ thr,   \
              const float* __restrict__ noise, const float* __restrict__ dt,  \
              const int* __restrict__ nw, float* __restrict__ out)
#define DEFROUND(NAME, R)                                                     \
  __global__ __launch_bounds__(BLOCK) void NAME ARGS {                        \
    ddm_round_body<R>(sv, rate, ndt, thr, noise, dt, nw, out);                \
  }
DEFROUND(ddm_r0, 0)   DEFROUND(ddm_r1, 1)   DEFROUND(ddm_r2, 2)
DEFROUND(ddm_r3, 3)   DEFROUND(ddm_r4, 4)   DEFROUND(ddm_r5, 5)
#undef DEFROUND
#undef ARGS

// readlane broadcast of a float (forces v_readlane, not ds_bpermute).
__device__ __forceinline__ float rdlane_f(float v, int j) {
  return __uint_as_float((uint32_t)__builtin_amdgcn_readlane((int)__float_as_uint(v), j));
}

// Tail: ONE WALKER PER WAVE. 64 lanes compute q_{t..t+63} in parallel, then a
// branchless EXACT fold with quarter snapshots (R7). R11: pairwise running
// max — mx = fmax(mx, fmax(|p_a|,|p_b|)) per 2 steps (fusable to v_max3,
// abs is a free input modifier). The p-chain (same fadds, same order) is
// untouched -> crossing detection & rescan bit-identical.
__global__ __launch_bounds__(256)
void ddm_tail(const float* __restrict__ sv_p, const float* __restrict__ rate_p,
              const float* __restrict__ ndt_p, const float* __restrict__ thr_p,
              const float* __restrict__ noise_p, const float* __restrict__ dt_p,
              const int* __restrict__ nw_p, float* __restrict__ out,
              int round, int t0) {
  int nw = *nw_p;
  float rate = *rate_p, ndt = *ndt_p, thr = *thr_p,
        noise = *noise_p, dt = *dt_p;
  float rate_dt = __fmul_rn(rate, dt);
  float sqrt_dt = __fsqrt_rn(dt);
  float A  = __fmul_rn(rate_dt, sqrt_dt);                    // uniform
  float B2 = __fmul_rn(__fmul_rn(noise, sqrt_dt), SQRT2_F);  // uniform

  int lane = threadIdx.x & 63;
  uint32_t wave = blockIdx.x * (256 / 64) + (threadIdx.x >> 6);
  uint32_t nwaves = gridDim.x * (256 / 64);
  uint32_t count = g_cnt[round];

  for (uint32_t k = wave; k < count; k += nwaves) {
    uint2 e = g_list[round & 1][k];
    int i = (int)e.x;
    float p = __uint_as_float(e.y);        // wave-uniform from here on
    int t = t0;
    int rts_i = NSTEPS;
    bool done = false;
    while (!done) {
      int valid = NSTEPS - t; if (valid > 64) valid = 64;
      int tl = t + (lane < valid ? lane : valid - 1);
      uint2 kk = g_keys[tl];               // coalesced 8B, L2-resident
      uint32_t b1, b2;
      tf2x32(kk.x, kk.y, 0u, (uint32_t)i, b1, b2);
      float ev = einv_from_bits(b1 ^ b2);
      float q = MAD(B2, ev, A);

      if (valid == 64) {
        // ---- branchless exact fold, quarter-snapshotted, pairwise max ----
        float s0 = p, mx0 = 0.0f, mx1 = 0.0f, mx2 = 0.0f, mx3 = 0.0f;
        #pragma unroll
        for (int j = 0; j < 16; j += 2) {
          float pa = __fadd_rn(p,  rdlane_f(q, j));
          float pb = __fadd_rn(pa, rdlane_f(q, j + 1));
          mx0 = fmaxf(mx0, fmaxf(fabsf(pa), fabsf(pb)));
          p = pb;
        }
        float s1 = p;
        #pragma unroll
        for (int j = 16; j < 32; j += 2) {
          float pa = __fadd_rn(p,  rdlane_f(q, j));
          float pb = __fadd_rn(pa, rdlane_f(q, j + 1));
          mx1 = fmaxf(mx1, fmaxf(fabsf(pa), fabsf(pb)));
          p = pb;
        }
        float s2 = p;
        #pragma unroll
        for (int j = 32; j < 48; j += 2) {
          float pa = __fadd_rn(p,  rdlane_f(q, j));
          float pb = __fadd_rn(pa, rdlane_f(q, j + 1));
          mx2 = fmaxf(mx2, fmaxf(fabsf(pa), fabsf(pb)));
          p = pb;
        }
        float s3 = p;
        #pragma unroll
        for (int j = 48; j < 64; j += 2) {
          float pa = __fadd_rn(p,  rdlane_f(q, j));
          float pb = __fadd_rn(pa, rdlane_f(q, j + 1));
          mx3 = fmaxf(mx3, fmaxf(fabsf(pa), fabsf(pb)));
          p = pb;
        }
        if (fmaxf(fmaxf(mx0, mx1), fmaxf(mx2, mx3)) >= thr) {
          // death block: first crossing lives in the FIRST quarter w/ mx>=thr
          float pr; int jb;
          if      (mx0 >= thr) { pr = s0; jb = 0;  }
          else if (mx1 >= thr) { pr = s1; jb = 16; }
          else if (mx2 >= thr) { pr = s2; jb = 32; }
          else                 { pr = s3; jb = 48; }
          for (int j = 0; j < 16; ++j) {   // exact re-scan from snapshot
            pr = __fadd_rn(pr, rdlane_f(q, jb + j));
            if (!(fabsf(pr) < thr)) {
              rts_i = t + jb + j + 1; p = pr; done = true; break;
            }
          }
        } else {
          t += 64;
          if (t >= NSTEPS) done = true;    // ran out the clock: rts = 3000
        }
      } else {
        // rare partial final block: original checked scan
        for (int j = 0; j < valid; ++j) {
          float qj = rdlane_f(q, j);
          p = __fadd_rn(p, qj);
          if (!(fabsf(p) < thr)) { rts_i = t + j + 1; done = true; break; }
        }
        if (!done) {
          t += valid;
          if (t >= NSTEPS) done = true;
        }
      }
    }
    if (lane == 0) {
      out[i] = __fadd_rn(ndt, __fmul_rn((float)rts_i, dt));
      out[nw + i] = (p <= -thr) ? 0.0f : 1.0f;
    }
  }
}

extern "C" void kernel_launch(void* const* d_in, const int* in_sizes, int n_in,
                              void* d_out, int out_size, void* d_ws, size_t ws_size,
                              hipStream_t stream) {
  const float* sv    = (const float*)d_in[0];
  const float* rate  = (const float*)d_in[1];
  const float* ndt   = (const float*)d_in[2];
  const float* thr   = (const float*)d_in[3];
  const float* noise = (const float*)d_in[4];
  const float* dt    = (const float*)d_in[5];
  const int*   nw    = (const int*)d_in[6];
  float* out = (float*)d_out;

  init_kernel<<<NKEYS / 256, 256, 0, stream>>>();
  ddm_r0<<<NBD, BLOCK, 0, stream>>>(sv, rate, ndt, thr, noise, dt, nw, out);
  ddm_r1<<<NBD, BLOCK, 0, stream>>>(sv, rate, ndt, thr, noise, dt, nw, out);
  ddm_r2<<<NBD, BLOCK, 0, stream>>>(sv, rate, ndt, thr, noise, dt, nw, out);
  ddm_r3<<<NBD, BLOCK, 0, stream>>>(sv, rate, ndt, thr, noise, dt, nw, out);
  ddm_r4<<<NBD, BLOCK, 0, stream>>>(sv, rate, ndt, thr, noise, dt, nw, out);
  ddm_r5<<<NBD, BLOCK, 0, stream>>>(sv, rate, ndt, thr, noise, dt, nw, out);
  ddm_tail<<<NBT, 256, 0, stream>>>(sv, rate, ndt, thr, noise, dt, nw, out,
                                    NDENSE, NDENSE * CHUNK);
}

// Round 13
// 504.008 us; speedup vs baseline: 1.2007x; 1.0290x over previous
//
#include <hip/hip_runtime.h>
#include <math.h>

#define NSTEPS 3000
#define NWALK  1048576
#define BLOCK  256
#define NBD    (NWALK / BLOCK)   // 4096 dense blocks
#define NDENSE 6                 // dense rounds cover t in [0, 384), 64 steps each
#define CHUNK  64
#define NBT    4096              // tail grid: 16384 waves
#define NKEYS  3072

// FMA contraction (R8: passed, absmax 0.09375; R11: 0.0625).
#define MAD(a, b, c) __fmaf_rn((a), (b), (c))

// Ping-pong survivor lists (i, p-bits), per-round counts, precomputed keys.
__device__ uint2    g_list[2][NWALK];
__device__ uint32_t g_cnt[16];
__device__ uint2    g_keys[NKEYS];

// Threefry-2x32, 20 rounds, exactly JAX's schedule.
__device__ __forceinline__ void tf2x32(uint32_t k0, uint32_t k1,
                                       uint32_t x0, uint32_t x1,
                                       uint32_t& o0, uint32_t& o1) {
  uint32_t ks2 = k0 ^ k1 ^ 0x1BD11BDAu;
  x0 += k0; x1 += k1;
#define TFR(r) { x0 += x1; x1 = (x1 << r) | (x1 >> (32 - r)); x1 ^= x0; }
  TFR(13) TFR(15) TFR(26) TFR(6)
  x0 += k1;  x1 += ks2 + 1u;
  TFR(17) TFR(29) TFR(16) TFR(24)
  x0 += ks2; x1 += k0 + 2u;
  TFR(13) TFR(15) TFR(26) TFR(6)
  x0 += k0;  x1 += k1 + 3u;
  TFR(17) TFR(29) TFR(16) TFR(24)
  x0 += k1;  x1 += ks2 + 4u;
  TFR(13) TFR(15) TFR(26) TFR(6)
  x0 += ks2; x1 += k0 + 5u;
#undef TFR
  o0 = x0; o1 = x1;
}

// init: per-step folded split keys (counter (0,t), key (0,0)) + zero counts.
__global__ void init_kernel() {   // <<<NKEYS/256, 256>>>
  int t = blockIdx.x * 256 + threadIdx.x;
  uint32_t a, b;
  tf2x32(0u, 0u, 0u, (uint32_t)t, a, b);
  g_keys[t] = make_uint2(a, b);
  if (blockIdx.x == 0 && threadIdx.x < 16) g_cnt[threadIdx.x] = 0u;
}

// XLA CPU's log.f32 (Cephes/Eigen-3.3 plog), FMA-contracted (R8-verified).
__device__ __forceinline__ float xla_cpu_log_f32(float s) {
  uint32_t bits = __float_as_uint(s);
  int emm0 = (int)(bits >> 23) - 0x7f;
  float e = __fadd_rn((float)emm0, 1.0f);
  float m = __uint_as_float((bits & 0x007fffffu) | 0x3f000000u);
  bool mlt = m < 0.70710677f;
  float tmp = mlt ? m : 0.0f;
  float x = __fsub_rn(m, 1.0f);
  e = __fsub_rn(e, mlt ? 1.0f : 0.0f);
  x = __fadd_rn(x, tmp);
  float x2 = __fmul_rn(x, x);
  float x3 = __fmul_rn(x2, x);
  float y, y1, y2;
  y  = MAD(7.0376836292e-2f,  x, -1.1514610310e-1f);
  y1 = MAD(-1.2420140846e-1f, x,  1.4249322787e-1f);
  y2 = MAD(2.0000714765e-1f,  x, -2.4999993993e-1f);
  y  = MAD(y,  x,  1.1676998740e-1f);
  y1 = MAD(y1, x, -1.6668057665e-1f);
  y2 = MAD(y2, x,  3.3333331174e-1f);
  y  = MAD(y, x3, y1);
  y  = MAD(y, x3, y2);
  y  = __fmul_rn(y, x3);
  y  = MAD(e, -2.12194440e-4f, y);
  x  = MAD(x2, -0.5f, x);
  x  = __fadd_rn(x, y);
  x  = MAD(e, 0.693359375f, x);
  return x;
}

// XLA EmitErfInv f32 (Giles): w = -log((1-x)*(1+x)), branch at w<5.
__device__ __forceinline__ float xla_erfinv_f32(float x) {
  float s = __fmul_rn(__fsub_rn(1.0f, x), __fadd_rn(1.0f, x));
  float w = -xla_cpu_log_f32(s);
  float p;
  if (w < 5.0f) {
    float v = __fsub_rn(w, 2.5f);
    p = 2.81022636e-08f;
    p = MAD(p, v, 3.43273939e-07f);
    p = MAD(p, v, -3.5233877e-06f);
    p = MAD(p, v, -4.39150654e-06f);
    p = MAD(p, v, 0.00021858087f);
    p = MAD(p, v, -0.00125372503f);
    p = MAD(p, v, -0.00417768164f);
    p = MAD(p, v, 0.246640727f);
    p = MAD(p, v, 1.50140941f);
  } else {
    float v = __fsub_rn(__fsqrt_rn(w), 3.0f);
    p = -0.000200214257f;
    p = MAD(p, v, 0.000100950558f);
    p = MAD(p, v, 0.00134934322f);
    p = MAD(p, v, -0.00367342844f);
    p = MAD(p, v, 0.00573950773f);
    p = MAD(p, v, -0.0076224613f);
    p = MAD(p, v, 0.00943887047f);
    p = MAD(p, v, 1.00167406f);
    p = MAD(p, v, 2.83297682f);
  }
  return __fmul_rn(p, x);
}

// Raw erfinv from rng bits; sqrt2/(rate,noise,sqrt_dt) folded into A/B2
// (R11-verified). fmax(MINVAL,u) clamp removed bit-exactly (provable no-op).
__device__ __forceinline__ float einv_from_bits(uint32_t bits) {
  const float MINVAL = __uint_as_float(0xBF7FFFFFu);   // nextafter(-1,0)
  float f = __uint_as_float((bits >> 9) | 0x3F800000u) - 1.0f;
  float u = MAD(f, 2.0f, MINVAL);
  return xla_erfinv_f32(u);
}

#define SQRT2_F __uint_as_float(0x3FB504F3u)

// Dense round: FROZEN R11 shape (best measured). LDS-key broadcast,
// predicated 4x16 partially-unrolled body, per-BLOCK aggregated atomic,
// deferred death-store. In-loop compaction disproven twice (R1, R10).
template<int R>
__device__ __forceinline__
void ddm_round_body(const float* __restrict__ sv_p, const float* __restrict__ rate_p,
                    const float* __restrict__ ndt_p, const float* __restrict__ thr_p,
                    const float* __restrict__ noise_p, const float* __restrict__ dt_p,
                    const int* __restrict__ nw_p, float* __restrict__ out) {
  constexpr int t0 = R * CHUNK;
  int nw = *nw_p;
  uint32_t count = (R == 0) ? (uint32_t)nw : g_cnt[R];
  if (blockIdx.x * BLOCK >= count) return;     // block-uniform: no barriers yet

  __shared__ uint2    skeys[CHUNK];
  __shared__ uint32_t s_woff[BLOCK / 64];
  __shared__ uint32_t s_base;
  if (threadIdx.x < CHUNK) {
    uint32_t a, b;
    tf2x32(0u, 0u, 0u, (uint32_t)(t0 + threadIdx.x), a, b);
    skeys[threadIdx.x] = make_uint2(a, b);
  }
  __syncthreads();

  uint32_t slot = blockIdx.x * BLOCK + threadIdx.x;
  bool alive = slot < count;                   // no wave early-return: barriers below
  float sv = *sv_p, rate = *rate_p, ndt = *ndt_p, thr = *thr_p,
        noise = *noise_p, dt = *dt_p;
  float rate_dt = __fmul_rn(rate, dt);
  float sqrt_dt = __fsqrt_rn(dt);
  float A  = __fmul_rn(rate_dt, sqrt_dt);                    // uniform
  float B2 = __fmul_rn(__fmul_rn(noise, sqrt_dt), SQRT2_F);  // uniform
  int lane = threadIdx.x & 63;
  int wv = threadIdx.x >> 6;

  int i = 0; float p = 0.0f;
  if (alive) {
    if (R == 0) { i = (int)slot; p = __fadd_rn(0.0f, sv); }
    else { uint2 e = g_list[R & 1][slot]; i = (int)e.x; p = __uint_as_float(e.y); }
  }

  int death_s = -1;
  #pragma clang loop unroll(disable)
  for (int c = 0; c < CHUNK / 16; ++c) {       // runtime outer: code stays 16-step
    #pragma unroll
    for (int j = 0; j < 16; ++j) {
      int s = c * 16 + j;
      if (alive) {                             // dead waves: execz skip, ~free
        uint2 k = skeys[s];                    // uniform s: broadcast, no conflicts
        uint32_t b1, b2;
        tf2x32(k.x, k.y, 0u, (uint32_t)i, b1, b2);
        float e = einv_from_bits(b1 ^ b2);
        p = __fadd_rn(p, MAD(B2, e, A));
        if (!(fabsf(p) < thr)) { death_s = s; alive = false; }
      }
    }
  }
  if (death_s >= 0) {                          // once per dying lane, post-loop
    float rts = (float)(t0 + death_s + 1);     // exact int == accumulated +1.0f
    out[i] = __fadd_rn(ndt, __fmul_rn(rts, dt));
    out[nw + i] = (p <= -thr) ? 0.0f : 1.0f;
  }

  // ---- per-block aggregated compaction: ONE atomic per block ----
  uint64_t m = __ballot(alive);
  if (lane == 0) s_woff[wv] = (uint32_t)__popcll((unsigned long long)m);
  __syncthreads();
  if (threadIdx.x == 0) {
    uint32_t tot = 0;
    #pragma unroll
    for (int w = 0; w < BLOCK / 64; ++w) {
      uint32_t c = s_woff[w]; s_woff[w] = tot; tot += c;   // exclusive prefix
    }
    s_base = tot ? atomicAdd(&g_cnt[R + 1], tot) : 0u;
  }
  __syncthreads();
  if (alive) {
    uint32_t pos = s_base + s_woff[wv] +
                   (uint32_t)__popcll((unsigned long long)(m & ((1ull << lane) - 1ull)));
    g_list[(R + 1) & 1][pos] = make_uint2((uint32_t)i, __float_as_uint(p));
  }
}

// Distinct kernel names per round so rocprof top-k decomposes the timeline.
#define ARGS (const float* __restrict__ sv, const float* __restrict__ rate,   \
              const float* __restrict__ ndt, const float* __restrict__ thr,   \
              const float* __restrict__ noise, const float* __restrict__ dt,  \
              const int* __restrict__ nw, float* __restrict__ out)
#define DEFROUND(NAME, R)                                                     \
  __global__ __launch_bounds__(BLOCK) void NAME ARGS {                        \
    ddm_round_body<R>(sv, rate, ndt, thr, noise, dt, nw, out);                \
  }
DEFROUND(ddm_r0, 0)   DEFROUND(ddm_r1, 1)   DEFROUND(ddm_r2, 2)
DEFROUND(ddm_r3, 3)   DEFROUND(ddm_r4, 4)   DEFROUND(ddm_r5, 5)
#undef DEFROUND
#undef ARGS

// readlane broadcast of a float (forces v_readlane, not ds_bpermute).
__device__ __forceinline__ float rdlane_f(float v, int j) {
  return __uint_as_float((uint32_t)__builtin_amdgcn_readlane((int)__float_as_uint(v), j));
}

// DPP move with additive identity: masked/invalid lanes yield 0.0f.
// R13 fix: __builtin_amdgcn_update_dpp requires integer-constant-expression
// args -> CTRL/ROW_MASK are template parameters (fold to ICE at call site).
template<int CTRL, int ROW_MASK>
__device__ __forceinline__ float dpp0_f(float x) {
  return __uint_as_float((uint32_t)__builtin_amdgcn_update_dpp(
      0, (int)__float_as_uint(x), CTRL, ROW_MASK, 0xf, true));
}

// Canonical GCN wave64 inclusive add-scan: row_shr 1/2/4/8 within 16-lane
// rows, then row_bcast15 (rows 1,3) and row_bcast31 (rows 2,3).
// 6 VALU adds, ~50cy chain. lane63 = sum of all 64 inputs.
__device__ __forceinline__ float wave_scan_add(float x) {
  x = __fadd_rn(x, dpp0_f<0x111, 0xf>(x));   // row_shr:1
  x = __fadd_rn(x, dpp0_f<0x112, 0xf>(x));   // row_shr:2
  x = __fadd_rn(x, dpp0_f<0x114, 0xf>(x));   // row_shr:4
  x = __fadd_rn(x, dpp0_f<0x118, 0xf>(x));   // row_shr:8
  x = __fadd_rn(x, dpp0_f<0x142, 0xa>(x));   // row_bcast:15 -> rows 1,3
  x = __fadd_rn(x, dpp0_f<0x143, 0xc>(x));   // row_bcast:31 -> rows 2,3
  return x;
}

// Tail: ONE WALKER PER WAVE. R12/R13: wave-parallel PREFIX SCAN replaces the
// serial readlane fold. 64 lanes compute q_{t..t+63}; a 6-step DPP scan
// yields all candidate p_j at once; crossing = ballot + ffs; NO rescan
// (detection is self-consistent with the scan's p_j). Dep chain per
// block-iter ~500cy -> ~220cy — the straggler/latency path that dominated
// the tail. Numerics: tree-order summation perturbs p by ulps/block vs the
// sequential chain (same near-threshold-shift class as R8's verified FMA
// contraction; tolerance 0.259, currently 0.0625).
__global__ __launch_bounds__(256)
void ddm_tail(const float* __restrict__ sv_p, const float* __restrict__ rate_p,
              const float* __restrict__ ndt_p, const float* __restrict__ thr_p,
              const float* __restrict__ noise_p, const float* __restrict__ dt_p,
              const int* __restrict__ nw_p, float* __restrict__ out,
              int round, int t0) {
  int nw = *nw_p;
  float rate = *rate_p, ndt = *ndt_p, thr = *thr_p,
        noise = *noise_p, dt = *dt_p;
  float rate_dt = __fmul_rn(rate, dt);
  float sqrt_dt = __fsqrt_rn(dt);
  float A  = __fmul_rn(rate_dt, sqrt_dt);                    // uniform
  float B2 = __fmul_rn(__fmul_rn(noise, sqrt_dt), SQRT2_F);  // uniform

  int lane = threadIdx.x & 63;
  uint32_t wave = blockIdx.x * (256 / 64) + (threadIdx.x >> 6);
  uint32_t nwaves = gridDim.x * (256 / 64);
  uint32_t count = g_cnt[round];

  for (uint32_t k = wave; k < count; k += nwaves) {
    uint2 e = g_list[round & 1][k];
    int i = (int)e.x;
    float p = __uint_as_float(e.y);        // wave-uniform from here on
    int t = t0;
    int rts_i = NSTEPS;
    bool done = false;
    while (!done) {
      int valid = NSTEPS - t; if (valid > 64) valid = 64;
      int tl = t + (lane < valid ? lane : valid - 1);
      uint2 kk = g_keys[tl];               // coalesced 8B, L2-resident
      uint32_t b1, b2;
      tf2x32(kk.x, kk.y, 0u, (uint32_t)i, b1, b2);
      float ev = einv_from_bits(b1 ^ b2);
      float q = MAD(B2, ev, A);            // per-lane step increment

      float sc = wave_scan_add(q);         // inclusive prefix (tree order)
      float pj = __fadd_rn(p, sc);         // candidate trajectory value
      uint64_t crossed = __ballot(!(fabsf(pj) < thr));
      if (valid < 64)
        crossed &= (1ull << valid) - 1ull; // ignore padded lanes
      if (crossed != 0ull) {
        int first = __ffsll((unsigned long long)crossed) - 1;
        rts_i = t + first + 1;
        p = rdlane_f(pj, first);
        done = true;
      } else {
        p = rdlane_f(pj, valid - 1);       // advance full block
        t += valid;
        if (t >= NSTEPS) done = true;      // ran out the clock: rts = 3000
      }
    }
    if (lane == 0) {
      out[i] = __fadd_rn(ndt, __fmul_rn((float)rts_i, dt));
      out[nw + i] = (p <= -thr) ? 0.0f : 1.0f;
    }
  }
}

extern "C" void kernel_launch(void* const* d_in, const int* in_sizes, int n_in,
                              void* d_out, int out_size, void* d_ws, size_t ws_size,
                              hipStream_t stream) {
  const float* sv    = (const float*)d_in[0];
  const float* rate  = (const float*)d_in[1];
  const float* ndt   = (const float*)d_in[2];
  const float* thr   = (const float*)d_in[3];
  const float* noise = (const float*)d_in[4];
  const float* dt    = (const float*)d_in[5];
  const int*   nw    = (const int*)d_in[6];
  float* out = (float*)d_out;

  init_kernel<<<NKEYS / 256, 256, 0, stream>>>();
  ddm_r0<<<NBD, BLOCK, 0, stream>>>(sv, rate, ndt, thr, noise, dt, nw, out);
  ddm_r1<<<NBD, BLOCK, 0, stream>>>(sv, rate, ndt, thr, noise, dt, nw, out);
  ddm_r2<<<NBD, BLOCK, 0, stream>>>(sv, rate, ndt, thr, noise, dt, nw, out);
  ddm_r3<<<NBD, BLOCK, 0, stream>>>(sv, rate, ndt, thr, noise, dt, nw, out);
  ddm_r4<<<NBD, BLOCK, 0, stream>>>(sv, rate, ndt, thr, noise, dt, nw, out);
  ddm_r5<<<NBD, BLOCK, 0, stream>>>(sv, rate, ndt, thr, noise, dt, nw, out);
  ddm_tail<<<NBT, 256, 0, stream>>>(sv, rate, ndt, thr, noise, dt, nw, out,
                                    NDENSE, NDENSE * CHUNK);
}

// Round 15
// 474.045 us; speedup vs baseline: 1.2766x; 1.0632x over previous
//
#include <hip/hip_runtime.h>
#include <math.h>

#define NSTEPS 3000
#define NWALK  1048576
#define BLOCK  256
#define NBD    (NWALK / BLOCK)   // 4096 dense blocks
#define NDENSE 4                 // R14: dense covers t in [0, 256); scan tail is
                                 // ~2.2x cheaper/iter than the old fold, so the
                                 // R7 equilibrium (384) moves left — r4/r5 were
                                 // latency-floored (<100 blocks, ~1 wave/SIMD).
#define CHUNK  64
#define NBT    4096              // tail grid: 16384 waves (~3.5 walkers/wave)
#define NKEYS  3072

// FMA contraction (R8: passed, absmax 0.09375; R11/R13: 0.0625).
#define MAD(a, b, c) __fmaf_rn((a), (b), (c))

// Ping-pong survivor lists (i, p-bits), per-round counts, precomputed keys.
__device__ uint2    g_list[2][NWALK];
__device__ uint32_t g_cnt[16];
__device__ uint2    g_keys[NKEYS];

// Threefry-2x32, 20 rounds, exactly JAX's schedule.
__device__ __forceinline__ void tf2x32(uint32_t k0, uint32_t k1,
                                       uint32_t x0, uint32_t x1,
                                       uint32_t& o0, uint32_t& o1) {
  uint32_t ks2 = k0 ^ k1 ^ 0x1BD11BDAu;
  x0 += k0; x1 += k1;
#define TFR(r) { x0 += x1; x1 = (x1 << r) | (x1 >> (32 - r)); x1 ^= x0; }
  TFR(13) TFR(15) TFR(26) TFR(6)
  x0 += k1;  x1 += ks2 + 1u;
  TFR(17) TFR(29) TFR(16) TFR(24)
  x0 += ks2; x1 += k0 + 2u;
  TFR(13) TFR(15) TFR(26) TFR(6)
  x0 += k0;  x1 += k1 + 3u;
  TFR(17) TFR(29) TFR(16) TFR(24)
  x0 += k1;  x1 += ks2 + 4u;
  TFR(13) TFR(15) TFR(26) TFR(6)
  x0 += ks2; x1 += k0 + 5u;
#undef TFR
  o0 = x0; o1 = x1;
}

// init: per-step folded split keys (counter (0,t), key (0,0)) + zero counts.
__global__ void init_kernel() {   // <<<NKEYS/256, 256>>>
  int t = blockIdx.x * 256 + threadIdx.x;
  uint32_t a, b;
  tf2x32(0u, 0u, 0u, (uint32_t)t, a, b);
  g_keys[t] = make_uint2(a, b);
  if (blockIdx.x == 0 && threadIdx.x < 16) g_cnt[threadIdx.x] = 0u;
}

// XLA CPU's log.f32 (Cephes/Eigen-3.3 plog), FMA-contracted (R8-verified).
__device__ __forceinline__ float xla_cpu_log_f32(float s) {
  uint32_t bits = __float_as_uint(s);
  int emm0 = (int)(bits >> 23) - 0x7f;
  float e = __fadd_rn((float)emm0, 1.0f);
  float m = __uint_as_float((bits & 0x007fffffu) | 0x3f000000u);
  bool mlt = m < 0.70710677f;
  float tmp = mlt ? m : 0.0f;
  float x = __fsub_rn(m, 1.0f);
  e = __fsub_rn(e, mlt ? 1.0f : 0.0f);
  x = __fadd_rn(x, tmp);
  float x2 = __fmul_rn(x, x);
  float x3 = __fmul_rn(x2, x);
  float y, y1, y2;
  y  = MAD(7.0376836292e-2f,  x, -1.1514610310e-1f);
  y1 = MAD(-1.2420140846e-1f, x,  1.4249322787e-1f);
  y2 = MAD(2.0000714765e-1f,  x, -2.4999993993e-1f);
  y  = MAD(y,  x,  1.1676998740e-1f);
  y1 = MAD(y1, x, -1.6668057665e-1f);
  y2 = MAD(y2, x,  3.3333331174e-1f);
  y  = MAD(y, x3, y1);
  y  = MAD(y, x3, y2);
  y  = __fmul_rn(y, x3);
  y  = MAD(e, -2.12194440e-4f, y);
  x  = MAD(x2, -0.5f, x);
  x  = __fadd_rn(x, y);
  x  = MAD(e, 0.693359375f, x);
  return x;
}

// XLA EmitErfInv f32 (Giles): w = -log((1-x)*(1+x)), branch at w<5.
__device__ __forceinline__ float xla_erfinv_f32(float x) {
  float s = __fmul_rn(__fsub_rn(1.0f, x), __fadd_rn(1.0f, x));
  float w = -xla_cpu_log_f32(s);
  float p;
  if (w < 5.0f) {
    float v = __fsub_rn(w, 2.5f);
    p = 2.81022636e-08f;
    p = MAD(p, v, 3.43273939e-07f);
    p = MAD(p, v, -3.5233877e-06f);
    p = MAD(p, v, -4.39150654e-06f);
    p = MAD(p, v, 0.00021858087f);
    p = MAD(p, v, -0.00125372503f);
    p = MAD(p, v, -0.00417768164f);
    p = MAD(p, v, 0.246640727f);
    p = MAD(p, v, 1.50140941f);
  } else {
    float v = __fsub_rn(__fsqrt_rn(w), 3.0f);
    p = -0.000200214257f;
    p = MAD(p, v, 0.000100950558f);
    p = MAD(p, v, 0.00134934322f);
    p = MAD(p, v, -0.00367342844f);
    p = MAD(p, v, 0.00573950773f);
    p = MAD(p, v, -0.0076224613f);
    p = MAD(p, v, 0.00943887047f);
    p = MAD(p, v, 1.00167406f);
    p = MAD(p, v, 2.83297682f);
  }
  return __fmul_rn(p, x);
}

// Raw erfinv from rng bits; sqrt2/(rate,noise,sqrt_dt) folded into A/B2
// (R11-verified). fmax(MINVAL,u) clamp removed bit-exactly (provable no-op).
__device__ __forceinline__ float einv_from_bits(uint32_t bits) {
  const float MINVAL = __uint_as_float(0xBF7FFFFFu);   // nextafter(-1,0)
  float f = __uint_as_float((bits >> 9) | 0x3F800000u) - 1.0f;
  float u = MAD(f, 2.0f, MINVAL);
  return xla_erfinv_f32(u);
}

#define SQRT2_F __uint_as_float(0x3FB504F3u)

// Dense round: FROZEN R11 shape (best measured). LDS-key broadcast,
// predicated 4x16 partially-unrolled body, per-BLOCK aggregated atomic,
// deferred death-store. In-loop compaction disproven twice (R1, R10).
template<int R>
__device__ __forceinline__
void ddm_round_body(const float* __restrict__ sv_p, const float* __restrict__ rate_p,
                    const float* __restrict__ ndt_p, const float* __restrict__ thr_p,
                    const float* __restrict__ noise_p, const float* __restrict__ dt_p,
                    const int* __restrict__ nw_p, float* __restrict__ out) {
  constexpr int t0 = R * CHUNK;
  int nw = *nw_p;
  uint32_t count = (R == 0) ? (uint32_t)nw : g_cnt[R];
  if (blockIdx.x * BLOCK >= count) return;     // block-uniform: no barriers yet

  __shared__ uint2    skeys[CHUNK];
  __shared__ uint32_t s_woff[BLOCK / 64];
  __shared__ uint32_t s_base;
  if (threadIdx.x < CHUNK) {
    uint32_t a, b;
    tf2x32(0u, 0u, 0u, (uint32_t)(t0 + threadIdx.x), a, b);
    skeys[threadIdx.x] = make_uint2(a, b);
  }
  __syncthreads();

  uint32_t slot = blockIdx.x * BLOCK + threadIdx.x;
  bool alive = slot < count;                   // no wave early-return: barriers below
  float sv = *sv_p, rate = *rate_p, ndt = *ndt_p, thr = *thr_p,
        noise = *noise_p, dt = *dt_p;
  float rate_dt = __fmul_rn(rate, dt);
  float sqrt_dt = __fsqrt_rn(dt);
  float A  = __fmul_rn(rate_dt, sqrt_dt);                    // uniform
  float B2 = __fmul_rn(__fmul_rn(noise, sqrt_dt), SQRT2_F);  // uniform
  int lane = threadIdx.x & 63;
  int wv = threadIdx.x >> 6;

  int i = 0; float p = 0.0f;
  if (alive) {
    if (R == 0) { i = (int)slot; p = __fadd_rn(0.0f, sv); }
    else { uint2 e = g_list[R & 1][slot]; i = (int)e.x; p = __uint_as_float(e.y); }
  }

  int death_s = -1;
  #pragma clang loop unroll(disable)
  for (int c = 0; c < CHUNK / 16; ++c) {       // runtime outer: code stays 16-step
    #pragma unroll
    for (int j = 0; j < 16; ++j) {
      int s = c * 16 + j;
      if (alive) {                             // dead waves: execz skip, ~free
        uint2 k = skeys[s];                    // uniform s: broadcast, no conflicts
        uint32_t b1, b2;
        tf2x32(k.x, k.y, 0u, (uint32_t)i, b1, b2);
        float e = einv_from_bits(b1 ^ b2);
        p = __fadd_rn(p, MAD(B2, e, A));
        if (!(fabsf(p) < thr)) { death_s = s; alive = false; }
      }
    }
  }
  if (death_s >= 0) {                          // once per dying lane, post-loop
    float rts = (float)(t0 + death_s + 1);     // exact int == accumulated +1.0f
    out[i] = __fadd_rn(ndt, __fmul_rn(rts, dt));
    out[nw + i] = (p <= -thr) ? 0.0f : 1.0f;
  }

  // ---- per-block aggregated compaction: ONE atomic per block ----
  uint64_t m = __ballot(alive);
  if (lane == 0) s_woff[wv] = (uint32_t)__popcll((unsigned long long)m);
  __syncthreads();
  if (threadIdx.x == 0) {
    uint32_t tot = 0;
    #pragma unroll
    for (int w = 0; w < BLOCK / 64; ++w) {
      uint32_t c = s_woff[w]; s_woff[w] = tot; tot += c;   // exclusive prefix
    }
    s_base = tot ? atomicAdd(&g_cnt[R + 1], tot) : 0u;
  }
  __syncthreads();
  if (alive) {
    uint32_t pos = s_base + s_woff[wv] +
                   (uint32_t)__popcll((unsigned long long)(m & ((1ull << lane) - 1ull)));
    g_list[(R + 1) & 1][pos] = make_uint2((uint32_t)i, __float_as_uint(p));
  }
}

// Distinct kernel names per round so rocprof top-k decomposes the timeline.
#define ARGS (const float* __restrict__ sv, const float* __restrict__ rate,   \
              const float* __restrict__ ndt, const float* __restrict__ thr,   \
              const float* __restrict__ noise, const float* __restrict__ dt,  \
              const int* __restrict__ nw, float* __restrict__ out)
#define DEFROUND(NAME, R)                                                     \
  __global__ __launch_bounds__(BLOCK) void NAME ARGS {                        \
    ddm_round_body<R>(sv, rate, ndt, thr, noise, dt, nw, out);                \
  }
DEFROUND(ddm_r0, 0)   DEFROUND(ddm_r1, 1)   DEFROUND(ddm_r2, 2)
DEFROUND(ddm_r3, 3)
#undef DEFROUND
#undef ARGS

// readlane broadcast of a float (forces v_readlane, not ds_bpermute).
__device__ __forceinline__ float rdlane_f(float v, int j) {
  return __uint_as_float((uint32_t)__builtin_amdgcn_readlane((int)__float_as_uint(v), j));
}

// DPP move with additive identity: masked/invalid lanes yield 0.0f.
// __builtin_amdgcn_update_dpp requires ICE args -> template parameters.
template<int CTRL, int ROW_MASK>
__device__ __forceinline__ float dpp0_f(float x) {
  return __uint_as_float((uint32_t)__builtin_amdgcn_update_dpp(
      0, (int)__float_as_uint(x), CTRL, ROW_MASK, 0xf, true));
}

// Canonical GCN wave64 inclusive add-scan: row_shr 1/2/4/8 within 16-lane
// rows, then row_bcast15 (rows 1,3) and row_bcast31 (rows 2,3).
// 6 VALU adds, ~50cy chain. lane63 = sum of all 64 inputs.
__device__ __forceinline__ float wave_scan_add(float x) {
  x = __fadd_rn(x, dpp0_f<0x111, 0xf>(x));   // row_shr:1
  x = __fadd_rn(x, dpp0_f<0x112, 0xf>(x));   // row_shr:2
  x = __fadd_rn(x, dpp0_f<0x114, 0xf>(x));   // row_shr:4
  x = __fadd_rn(x, dpp0_f<0x118, 0xf>(x));   // row_shr:8
  x = __fadd_rn(x, dpp0_f<0x142, 0xa>(x));   // row_bcast:15 -> rows 1,3
  x = __fadd_rn(x, dpp0_f<0x143, 0xc>(x));   // row_bcast:31 -> rows 2,3
  return x;
}

// Tail: ONE WALKER PER WAVE, wave-parallel DPP prefix scan (R13-verified:
// passed, absmax 0.0625). 64 lanes compute q_{t..t+63}; 6-step scan yields
// all candidate p_j; crossing = ballot + ffs; no rescan. Handles t0=256's
// larger walker population with full TLP (57k walkers / 16k waves).
__global__ __launch_bounds__(256)
void ddm_tail(const float* __restrict__ sv_p, const float* __restrict__ rate_p,
              const float* __restrict__ ndt_p, const float* __restrict__ thr_p,
              const float* __restrict__ noise_p, const float* __restrict__ dt_p,
              const int* __restrict__ nw_p, float* __restrict__ out,
              int round, int t0) {
  int nw = *nw_p;
  float rate = *rate_p, ndt = *ndt_p, thr = *thr_p,
        noise = *noise_p, dt = *dt_p;
  float rate_dt = __fmul_rn(rate, dt);
  float sqrt_dt = __fsqrt_rn(dt);
  float A  = __fmul_rn(rate_dt, sqrt_dt);                    // uniform
  float B2 = __fmul_rn(__fmul_rn(noise, sqrt_dt), SQRT2_F);  // uniform

  int lane = threadIdx.x & 63;
  uint32_t wave = blockIdx.x * (256 / 64) + (threadIdx.x >> 6);
  uint32_t nwaves = gridDim.x * (256 / 64);
  uint32_t count = g_cnt[round];

  for (uint32_t k = wave; k < count; k += nwaves) {
    uint2 e = g_list[round & 1][k];
    int i = (int)e.x;
    float p = __uint_as_float(e.y);        // wave-uniform from here on
    int t = t0;
    int rts_i = NSTEPS;
    bool done = false;
    while (!done) {
      int valid = NSTEPS - t; if (valid > 64) valid = 64;
      int tl = t + (lane < valid ? lane : valid - 1);
      uint2 kk = g_keys[tl];               // coalesced 8B, L2-resident
      uint32_t b1, b2;
      tf2x32(kk.x, kk.y, 0u, (uint32_t)i, b1, b2);
      float ev = einv_from_bits(b1 ^ b2);
      float q = MAD(B2, ev, A);            // per-lane step increment

      float sc = wave_scan_add(q);         // inclusive prefix (tree order)
      float pj = __fadd_rn(p, sc);         // candidate trajectory value
      uint64_t crossed = __ballot(!(fabsf(pj) < thr));
      if (valid < 64)
        crossed &= (1ull << valid) - 1ull; // ignore padded lanes
      if (crossed != 0ull) {
        int first = __ffsll((unsigned long long)crossed) - 1;
        rts_i = t + first + 1;
        p = rdlane_f(pj, first);
        done = true;
      } else {
        p = rdlane_f(pj, valid - 1);       // advance full block
        t += valid;
        if (t >= NSTEPS) done = true;      // ran out the clock: rts = 3000
      }
    }
    if (lane == 0) {
      out[i] = __fadd_rn(ndt, __fmul_rn((float)rts_i, dt));
      out[nw + i] = (p <= -thr) ? 0.0f : 1.0f;
    }
  }
}

extern "C" void kernel_launch(void* const* d_in, const int* in_sizes, int n_in,
                              void* d_out, int out_size, void* d_ws, size_t ws_size,
                              hipStream_t stream) {
  const float* sv    = (const float*)d_in[0];
  const float* rate  = (const float*)d_in[1];
  const float* ndt   = (const float*)d_in[2];
  const float* thr   = (const float*)d_in[3];
  const float* noise = (const float*)d_in[4];
  const float* dt    = (const float*)d_in[5];
  const int*   nw    = (const int*)d_in[6];
  float* out = (float*)d_out;

  init_kernel<<<NKEYS / 256, 256, 0, stream>>>();
  ddm_r0<<<NBD, BLOCK, 0, stream>>>(sv, rate, ndt, thr, noise, dt, nw, out);
  ddm_r1<<<NBD, BLOCK, 0, stream>>>(sv, rate, ndt, thr, noise, dt, nw, out);
  ddm_r2<<<NBD, BLOCK, 0, stream>>>(sv, rate, ndt, thr, noise, dt, nw, out);
  ddm_r3<<<NBD, BLOCK, 0, stream>>>(sv, rate, ndt, thr, noise, dt, nw, out);
  ddm_tail<<<NBT, 256, 0, stream>>>(sv, rate, ndt, thr, noise, dt, nw, out,
                                    NDENSE, NDENSE * CHUNK);
}

// Round 16
// 464.333 us; speedup vs baseline: 1.3033x; 1.0209x over previous
//
#include <hip/hip_runtime.h>
#include <math.h>

#define NSTEPS 3000
#define NWALK  1048576
#define BLOCK  256
#define NBD    (NWALK / BLOCK)   // 4096 dense blocks
#define NDENSE 3                 // R16: dense covers t in [0, 192). Scan-tail
                                 // cost/walker-step ~= dense's, with full TLP
                                 // and no per-round floor -> boundary moves
                                 // left again (R15: 6->4 won -30us).
#define CHUNK  64
#define NBT    4096              // tail grid: 16384 waves (~10 walkers/wave)
#define NKEYS  3072

// FMA contraction (R8: passed, absmax 0.09375; R11/R13/R15: 0.0625).
#define MAD(a, b, c) __fmaf_rn((a), (b), (c))

// Ping-pong survivor lists (i, p-bits), per-round counts, precomputed keys.
__device__ uint2    g_list[2][NWALK];
__device__ uint32_t g_cnt[16];
__device__ uint2    g_keys[NKEYS];

// Threefry-2x32, 20 rounds, exactly JAX's schedule.
__device__ __forceinline__ void tf2x32(uint32_t k0, uint32_t k1,
                                       uint32_t x0, uint32_t x1,
                                       uint32_t& o0, uint32_t& o1) {
  uint32_t ks2 = k0 ^ k1 ^ 0x1BD11BDAu;
  x0 += k0; x1 += k1;
#define TFR(r) { x0 += x1; x1 = (x1 << r) | (x1 >> (32 - r)); x1 ^= x0; }
  TFR(13) TFR(15) TFR(26) TFR(6)
  x0 += k1;  x1 += ks2 + 1u;
  TFR(17) TFR(29) TFR(16) TFR(24)
  x0 += ks2; x1 += k0 + 2u;
  TFR(13) TFR(15) TFR(26) TFR(6)
  x0 += k0;  x1 += k1 + 3u;
  TFR(17) TFR(29) TFR(16) TFR(24)
  x0 += k1;  x1 += ks2 + 4u;
  TFR(13) TFR(15) TFR(26) TFR(6)
  x0 += ks2; x1 += k0 + 5u;
#undef TFR
  o0 = x0; o1 = x1;
}

// init: per-step folded split keys (counter (0,t), key (0,0)) + zero counts.
__global__ void init_kernel() {   // <<<NKEYS/256, 256>>>
  int t = blockIdx.x * 256 + threadIdx.x;
  uint32_t a, b;
  tf2x32(0u, 0u, 0u, (uint32_t)t, a, b);
  g_keys[t] = make_uint2(a, b);
  if (blockIdx.x == 0 && threadIdx.x < 16) g_cnt[threadIdx.x] = 0u;
}

// XLA CPU's log.f32 (Cephes/Eigen-3.3 plog), FMA-contracted (R8-verified).
__device__ __forceinline__ float xla_cpu_log_f32(float s) {
  uint32_t bits = __float_as_uint(s);
  int emm0 = (int)(bits >> 23) - 0x7f;
  float e = __fadd_rn((float)emm0, 1.0f);
  float m = __uint_as_float((bits & 0x007fffffu) | 0x3f000000u);
  bool mlt = m < 0.70710677f;
  float tmp = mlt ? m : 0.0f;
  float x = __fsub_rn(m, 1.0f);
  e = __fsub_rn(e, mlt ? 1.0f : 0.0f);
  x = __fadd_rn(x, tmp);
  float x2 = __fmul_rn(x, x);
  float x3 = __fmul_rn(x2, x);
  float y, y1, y2;
  y  = MAD(7.0376836292e-2f,  x, -1.1514610310e-1f);
  y1 = MAD(-1.2420140846e-1f, x,  1.4249322787e-1f);
  y2 = MAD(2.0000714765e-1f,  x, -2.4999993993e-1f);
  y  = MAD(y,  x,  1.1676998740e-1f);
  y1 = MAD(y1, x, -1.6668057665e-1f);
  y2 = MAD(y2, x,  3.3333331174e-1f);
  y  = MAD(y, x3, y1);
  y  = MAD(y, x3, y2);
  y  = __fmul_rn(y, x3);
  y  = MAD(e, -2.12194440e-4f, y);
  x  = MAD(x2, -0.5f, x);
  x  = __fadd_rn(x, y);
  x  = MAD(e, 0.693359375f, x);
  return x;
}

// XLA EmitErfInv f32 (Giles): w = -log((1-x)*(1+x)), branch at w<5.
__device__ __forceinline__ float xla_erfinv_f32(float x) {
  float s = __fmul_rn(__fsub_rn(1.0f, x), __fadd_rn(1.0f, x));
  float w = -xla_cpu_log_f32(s);
  float p;
  if (w < 5.0f) {
    float v = __fsub_rn(w, 2.5f);
    p = 2.81022636e-08f;
    p = MAD(p, v, 3.43273939e-07f);
    p = MAD(p, v, -3.5233877e-06f);
    p = MAD(p, v, -4.39150654e-06f);
    p = MAD(p, v, 0.00021858087f);
    p = MAD(p, v, -0.00125372503f);
    p = MAD(p, v, -0.00417768164f);
    p = MAD(p, v, 0.246640727f);
    p = MAD(p, v, 1.50140941f);
  } else {
    float v = __fsub_rn(__fsqrt_rn(w), 3.0f);
    p = -0.000200214257f;
    p = MAD(p, v, 0.000100950558f);
    p = MAD(p, v, 0.00134934322f);
    p = MAD(p, v, -0.00367342844f);
    p = MAD(p, v, 0.00573950773f);
    p = MAD(p, v, -0.0076224613f);
    p = MAD(p, v, 0.00943887047f);
    p = MAD(p, v, 1.00167406f);
    p = MAD(p, v, 2.83297682f);
  }
  return __fmul_rn(p, x);
}

// Raw erfinv from rng bits; sqrt2/(rate,noise,sqrt_dt) folded into A/B2
// (R11-verified). fmax(MINVAL,u) clamp removed bit-exactly (provable no-op).
__device__ __forceinline__ float einv_from_bits(uint32_t bits) {
  const float MINVAL = __uint_as_float(0xBF7FFFFFu);   // nextafter(-1,0)
  float f = __uint_as_float((bits >> 9) | 0x3F800000u) - 1.0f;
  float u = MAD(f, 2.0f, MINVAL);
  return xla_erfinv_f32(u);
}

#define SQRT2_F __uint_as_float(0x3FB504F3u)

// Dense round: FROZEN R11 shape (best measured). LDS-key broadcast,
// predicated 4x16 partially-unrolled body, per-BLOCK aggregated atomic,
// deferred death-store. In-loop compaction disproven twice (R1, R10).
template<int R>
__device__ __forceinline__
void ddm_round_body(const float* __restrict__ sv_p, const float* __restrict__ rate_p,
                    const float* __restrict__ ndt_p, const float* __restrict__ thr_p,
                    const float* __restrict__ noise_p, const float* __restrict__ dt_p,
                    const int* __restrict__ nw_p, float* __restrict__ out) {
  constexpr int t0 = R * CHUNK;
  int nw = *nw_p;
  uint32_t count = (R == 0) ? (uint32_t)nw : g_cnt[R];
  if (blockIdx.x * BLOCK >= count) return;     // block-uniform: no barriers yet

  __shared__ uint2    skeys[CHUNK];
  __shared__ uint32_t s_woff[BLOCK / 64];
  __shared__ uint32_t s_base;
  if (threadIdx.x < CHUNK) {
    uint32_t a, b;
    tf2x32(0u, 0u, 0u, (uint32_t)(t0 + threadIdx.x), a, b);
    skeys[threadIdx.x] = make_uint2(a, b);
  }
  __syncthreads();

  uint32_t slot = blockIdx.x * BLOCK + threadIdx.x;
  bool alive = slot < count;                   // no wave early-return: barriers below
  float sv = *sv_p, rate = *rate_p, ndt = *ndt_p, thr = *thr_p,
        noise = *noise_p, dt = *dt_p;
  float rate_dt = __fmul_rn(rate, dt);
  float sqrt_dt = __fsqrt_rn(dt);
  float A  = __fmul_rn(rate_dt, sqrt_dt);                    // uniform
  float B2 = __fmul_rn(__fmul_rn(noise, sqrt_dt), SQRT2_F);  // uniform
  int lane = threadIdx.x & 63;
  int wv = threadIdx.x >> 6;

  int i = 0; float p = 0.0f;
  if (alive) {
    if (R == 0) { i = (int)slot; p = __fadd_rn(0.0f, sv); }
    else { uint2 e = g_list[R & 1][slot]; i = (int)e.x; p = __uint_as_float(e.y); }
  }

  int death_s = -1;
  #pragma clang loop unroll(disable)
  for (int c = 0; c < CHUNK / 16; ++c) {       // runtime outer: code stays 16-step
    #pragma unroll
    for (int j = 0; j < 16; ++j) {
      int s = c * 16 + j;
      if (alive) {                             // dead waves: execz skip, ~free
        uint2 k = skeys[s];                    // uniform s: broadcast, no conflicts
        uint32_t b1, b2;
        tf2x32(k.x, k.y, 0u, (uint32_t)i, b1, b2);
        float e = einv_from_bits(b1 ^ b2);
        p = __fadd_rn(p, MAD(B2, e, A));
        if (!(fabsf(p) < thr)) { death_s = s; alive = false; }
      }
    }
  }
  if (death_s >= 0) {                          // once per dying lane, post-loop
    float rts = (float)(t0 + death_s + 1);     // exact int == accumulated +1.0f
    out[i] = __fadd_rn(ndt, __fmul_rn(rts, dt));
    out[nw + i] = (p <= -thr) ? 0.0f : 1.0f;
  }

  // ---- per-block aggregated compaction: ONE atomic per block ----
  uint64_t m = __ballot(alive);
  if (lane == 0) s_woff[wv] = (uint32_t)__popcll((unsigned long long)m);
  __syncthreads();
  if (threadIdx.x == 0) {
    uint32_t tot = 0;
    #pragma unroll
    for (int w = 0; w < BLOCK / 64; ++w) {
      uint32_t c = s_woff[w]; s_woff[w] = tot; tot += c;   // exclusive prefix
    }
    s_base = tot ? atomicAdd(&g_cnt[R + 1], tot) : 0u;
  }
  __syncthreads();
  if (alive) {
    uint32_t pos = s_base + s_woff[wv] +
                   (uint32_t)__popcll((unsigned long long)(m & ((1ull << lane) - 1ull)));
    g_list[(R + 1) & 1][pos] = make_uint2((uint32_t)i, __float_as_uint(p));
  }
}

// Distinct kernel names per round so rocprof top-k decomposes the timeline.
#define ARGS (const float* __restrict__ sv, const float* __restrict__ rate,   \
              const float* __restrict__ ndt, const float* __restrict__ thr,   \
              const float* __restrict__ noise, const float* __restrict__ dt,  \
              const int* __restrict__ nw, float* __restrict__ out)
#define DEFROUND(NAME, R)                                                     \
  __global__ __launch_bounds__(BLOCK) void NAME ARGS {                        \
    ddm_round_body<R>(sv, rate, ndt, thr, noise, dt, nw, out);                \
  }
DEFROUND(ddm_r0, 0)   DEFROUND(ddm_r1, 1)   DEFROUND(ddm_r2, 2)
#undef DEFROUND
#undef ARGS

// readlane broadcast of a float (forces v_readlane, not ds_bpermute).
__device__ __forceinline__ float rdlane_f(float v, int j) {
  return __uint_as_float((uint32_t)__builtin_amdgcn_readlane((int)__float_as_uint(v), j));
}

// DPP move with additive identity: masked/invalid lanes yield 0.0f.
// __builtin_amdgcn_update_dpp requires ICE args -> template parameters.
template<int CTRL, int ROW_MASK>
__device__ __forceinline__ float dpp0_f(float x) {
  return __uint_as_float((uint32_t)__builtin_amdgcn_update_dpp(
      0, (int)__float_as_uint(x), CTRL, ROW_MASK, 0xf, true));
}

// Canonical GCN wave64 inclusive add-scan: row_shr 1/2/4/8 within 16-lane
// rows, then row_bcast15 (rows 1,3) and row_bcast31 (rows 2,3).
// 6 VALU adds, ~50cy chain. lane63 = sum of all 64 inputs.
__device__ __forceinline__ float wave_scan_add(float x) {
  x = __fadd_rn(x, dpp0_f<0x111, 0xf>(x));   // row_shr:1
  x = __fadd_rn(x, dpp0_f<0x112, 0xf>(x));   // row_shr:2
  x = __fadd_rn(x, dpp0_f<0x114, 0xf>(x));   // row_shr:4
  x = __fadd_rn(x, dpp0_f<0x118, 0xf>(x));   // row_shr:8
  x = __fadd_rn(x, dpp0_f<0x142, 0xa>(x));   // row_bcast:15 -> rows 1,3
  x = __fadd_rn(x, dpp0_f<0x143, 0xc>(x));   // row_bcast:31 -> rows 2,3
  return x;
}

// Tail: ONE WALKER PER WAVE, wave-parallel DPP prefix scan (R13/R15-verified:
// passed, absmax 0.0625). 64 lanes compute q_{t..t+63}; 6-step scan yields
// all candidate p_j; crossing = ballot + ffs; no rescan. From t0=192:
// ~150-190k walkers over 16k waves, grid-stride balanced.
__global__ __launch_bounds__(256)
void ddm_tail(const float* __restrict__ sv_p, const float* __restrict__ rate_p,
              const float* __restrict__ ndt_p, const float* __restrict__ thr_p,
              const float* __restrict__ noise_p, const float* __restrict__ dt_p,
              const int* __restrict__ nw_p, float* __restrict__ out,
              int round, int t0) {
  int nw = *nw_p;
  float rate = *rate_p, ndt = *ndt_p, thr = *thr_p,
        noise = *noise_p, dt = *dt_p;
  float rate_dt = __fmul_rn(rate, dt);
  float sqrt_dt = __fsqrt_rn(dt);
  float A  = __fmul_rn(rate_dt, sqrt_dt);                    // uniform
  float B2 = __fmul_rn(__fmul_rn(noise, sqrt_dt), SQRT2_F);  // uniform

  int lane = threadIdx.x & 63;
  uint32_t wave = blockIdx.x * (256 / 64) + (threadIdx.x >> 6);
  uint32_t nwaves = gridDim.x * (256 / 64);
  uint32_t count = g_cnt[round];

  for (uint32_t k = wave; k < count; k += nwaves) {
    uint2 e = g_list[round & 1][k];
    int i = (int)e.x;
    float p = __uint_as_float(e.y);        // wave-uniform from here on
    int t = t0;
    int rts_i = NSTEPS;
    bool done = false;
    while (!done) {
      int valid = NSTEPS - t; if (valid > 64) valid = 64;
      int tl = t + (lane < valid ? lane : valid - 1);
      uint2 kk = g_keys[tl];               // coalesced 8B, L2-resident
      uint32_t b1, b2;
      tf2x32(kk.x, kk.y, 0u, (uint32_t)i, b1, b2);
      float ev = einv_from_bits(b1 ^ b2);
      float q = MAD(B2, ev, A);            // per-lane step increment

      float sc = wave_scan_add(q);         // inclusive prefix (tree order)
      float pj = __fadd_rn(p, sc);         // candidate trajectory value
      uint64_t crossed = __ballot(!(fabsf(pj) < thr));
      if (valid < 64)
        crossed &= (1ull << valid) - 1ull; // ignore padded lanes
      if (crossed != 0ull) {
        int first = __ffsll((unsigned long long)crossed) - 1;
        rts_i = t + first + 1;
        p = rdlane_f(pj, first);
        done = true;
      } else {
        p = rdlane_f(pj, valid - 1);       // advance full block
        t += valid;
        if (t >= NSTEPS) done = true;      // ran out the clock: rts = 3000
      }
    }
    if (lane == 0) {
      out[i] = __fadd_rn(ndt, __fmul_rn((float)rts_i, dt));
      out[nw + i] = (p <= -thr) ? 0.0f : 1.0f;
    }
  }
}

extern "C" void kernel_launch(void* const* d_in, const int* in_sizes, int n_in,
                              void* d_out, int out_size, void* d_ws, size_t ws_size,
                              hipStream_t stream) {
  const float* sv    = (const float*)d_in[0];
  const float* rate  = (const float*)d_in[1];
  const float* ndt   = (const float*)d_in[2];
  const float* thr   = (const float*)d_in[3];
  const float* noise = (const float*)d_in[4];
  const float* dt    = (const float*)d_in[5];
  const int*   nw    = (const int*)d_in[6];
  float* out = (float*)d_out;

  init_kernel<<<NKEYS / 256, 256, 0, stream>>>();
  ddm_r0<<<NBD, BLOCK, 0, stream>>>(sv, rate, ndt, thr, noise, dt, nw, out);
  ddm_r1<<<NBD, BLOCK, 0, stream>>>(sv, rate, ndt, thr, noise, dt, nw, out);
  ddm_r2<<<NBD, BLOCK, 0, stream>>>(sv, rate, ndt, thr, noise, dt, nw, out);
  ddm_tail<<<NBT, 256, 0, stream>>>(sv, rate, ndt, thr, noise, dt, nw, out,
                                    NDENSE, NDENSE * CHUNK);
}